// Round 2
// baseline (1545.077 us; speedup 1.0000x reference)
//
#include <hip/hip_runtime.h>
#include <math.h>

#define NN 100000
#define NE 1600000
#define D 128
#define BN_EPS 1e-5f

// ws layout: dinv [0,400000) | deg [400000,800000) | sums [800000,801024)

// ---------------- kernel 1: init deg=1 (self-loop), zero BN sums ----------------
__global__ void k_init(unsigned* __restrict__ deg, float* __restrict__ sums) {
    int i = blockIdx.x * blockDim.x + threadIdx.x;
    if (i < NN) deg[i] = 1u;
    if (i < 256) sums[i] = 0.f;
}

// ---------------- kernel 2: degree over source (row) indices --------------------
__global__ void k_deg(const int* __restrict__ ei, unsigned* __restrict__ deg) {
    int e = blockIdx.x * blockDim.x + threadIdx.x;
    if (e >= NE) return;
    int r = ei[e];
    int c = ei[NE + e];
    if (r != c) atomicAdd(&deg[r], 1u);
}

// ---------------- kernel 3: dinv = rsqrt(deg) (deg >= 1 always) -----------------
__global__ void k_dinv(const unsigned* __restrict__ deg, float* __restrict__ dinv) {
    int i = blockIdx.x * blockDim.x + threadIdx.x;
    if (i < NN) dinv[i] = rsqrtf((float)deg[i]);
}

// ------------- kernel 4: out = dinv[i]^2 * x[i]  (self-loop term, full init) ----
__global__ void k_selfagg(const float* __restrict__ x, const float* __restrict__ dinv,
                          float* __restrict__ out) {
    int idx = blockIdx.x * blockDim.x + threadIdx.x;  // float4 index
    if (idx >= NN * (D / 4)) return;
    int i = idx >> 5;  // 32 float4 per row
    float d = dinv[i];
    float s = d * d;
    float4 v = ((const float4*)x)[idx];
    v.x *= s; v.y *= s; v.z *= s; v.w *= s;
    ((float4*)out)[idx] = v;
}

// ------------- kernel 5: edge aggregation into out, one wave per edge -----------
__global__ __launch_bounds__(256) void k_edges(const int* __restrict__ ei,
                                               const float* __restrict__ x,
                                               const float* __restrict__ dinv,
                                               float* __restrict__ out) {
    const int lane = threadIdx.x & 63;
    const int gw = (blockIdx.x * blockDim.x + threadIdx.x) >> 6;
    const int nw = (gridDim.x * blockDim.x) >> 6;
    for (int e = gw; e < NE; e += nw) {
        int r = ei[e];
        int c = ei[NE + e];
        if (r == c) continue;  // ew = 0 for self-loop edges in the raw list
        float nrm = dinv[r] * dinv[c];
        float2 xv = *(const float2*)&x[r * D + 2 * lane];
        float* op = &out[c * D + 2 * lane];
        unsafeAtomicAdd(op,     nrm * xv.x);
        unsafeAtomicAdd(op + 1, nrm * xv.y);
    }
}

// ------------- kernel 6: in-place out_row = relu(out_row @ W + b) ---------------
// Safe in-place: each 4-row tile is owned by exactly one wave; all loads of the
// tile feed the FMA chain and therefore precede the stores.
__global__ __launch_bounds__(256) void k_gemmip(float* __restrict__ out,
                                                const float* __restrict__ W,
                                                const float* __restrict__ b) {
    __shared__ float Wl[D * D];  // 64 KB
    for (int t = threadIdx.x; t < D * D / 4; t += 256)
        ((float4*)Wl)[t] = ((const float4*)W)[t];
    __syncthreads();

    const int lane = threadIdx.x & 63;
    const int wave = threadIdx.x >> 6;
    const float blo = b[lane], bhi = b[lane + 64];
    const int gw = blockIdx.x * 4 + wave;
    const int nw = gridDim.x * 4;

    for (int tile = gw; tile < NN / 4; tile += nw) {
        float* r0 = out + (tile * 4 + 0) * D;
        float* r1 = out + (tile * 4 + 1) * D;
        float* r2 = out + (tile * 4 + 2) * D;
        float* r3 = out + (tile * 4 + 3) * D;
        float a0l = 0.f, a0h = 0.f, a1l = 0.f, a1h = 0.f;
        float a2l = 0.f, a2h = 0.f, a3l = 0.f, a3h = 0.f;
        for (int k4 = 0; k4 < D; k4 += 4) {
            float4 x0 = *(const float4*)&r0[k4];
            float4 x1 = *(const float4*)&r1[k4];
            float4 x2 = *(const float4*)&r2[k4];
            float4 x3 = *(const float4*)&r3[k4];
            float xa0[4] = {x0.x, x0.y, x0.z, x0.w};
            float xa1[4] = {x1.x, x1.y, x1.z, x1.w};
            float xa2[4] = {x2.x, x2.y, x2.z, x2.w};
            float xa3[4] = {x3.x, x3.y, x3.z, x3.w};
            #pragma unroll
            for (int j = 0; j < 4; ++j) {
                float wlo = Wl[(k4 + j) * D + lane];
                float whi = Wl[(k4 + j) * D + 64 + lane];
                a0l = fmaf(xa0[j], wlo, a0l); a0h = fmaf(xa0[j], whi, a0h);
                a1l = fmaf(xa1[j], wlo, a1l); a1h = fmaf(xa1[j], whi, a1h);
                a2l = fmaf(xa2[j], wlo, a2l); a2h = fmaf(xa2[j], whi, a2h);
                a3l = fmaf(xa3[j], wlo, a3l); a3h = fmaf(xa3[j], whi, a3h);
            }
        }
        r0[lane] = fmaxf(a0l + blo, 0.f); r0[lane + 64] = fmaxf(a0h + bhi, 0.f);
        r1[lane] = fmaxf(a1l + blo, 0.f); r1[lane + 64] = fmaxf(a1h + bhi, 0.f);
        r2[lane] = fmaxf(a2l + blo, 0.f); r2[lane + 64] = fmaxf(a2h + bhi, 0.f);
        r3[lane] = fmaxf(a3l + blo, 0.f); r3[lane + 64] = fmaxf(a3h + bhi, 0.f);
    }
}

// ------------- kernel 7: BN stats (sum, sumsq per channel) ----------------------
__global__ __launch_bounds__(256) void k_stats(const float* __restrict__ out,
                                               float* __restrict__ sums) {
    const int c  = threadIdx.x & 127;
    const int rg = threadIdx.x >> 7;
    float s = 0.f, s2 = 0.f;
    for (int row = blockIdx.x * 2 + rg; row < NN; row += gridDim.x * 2) {
        float v = out[row * D + c];
        s += v;
        s2 = fmaf(v, v, s2);
    }
    __shared__ float r1[128], r2[128];
    if (rg == 1) { r1[c] = s; r2[c] = s2; }
    __syncthreads();
    if (rg == 0) {
        s += r1[c];
        s2 += r2[c];
        unsafeAtomicAdd(&sums[c], s);
        unsafeAtomicAdd(&sums[128 + c], s2);
    }
}

// ------------- kernel 8: out = out * scale + shift  (BN affine) -----------------
__global__ __launch_bounds__(256) void k_apply(float* __restrict__ out,
                                               const float* __restrict__ gamma,
                                               const float* __restrict__ beta,
                                               const float* __restrict__ sums) {
    const float invN = 1.f / (float)NN;
    const int tid = blockIdx.x * blockDim.x + threadIdx.x;
    const int stride = gridDim.x * blockDim.x;  // multiple of 32 -> channel-stable
    const int c4 = (tid & 31) * 4;

    float4 g4 = *(const float4*)&gamma[c4];
    float4 be = *(const float4*)&beta[c4];
    float4 s4 = *(const float4*)&sums[c4];
    float4 q4 = *(const float4*)&sums[128 + c4];

    float mx = s4.x * invN, my = s4.y * invN, mz = s4.z * invN, mw = s4.w * invN;
    float scx = g4.x * rsqrtf(fmaxf(q4.x * invN - mx * mx, 0.f) + BN_EPS);
    float scy = g4.y * rsqrtf(fmaxf(q4.y * invN - my * my, 0.f) + BN_EPS);
    float scz = g4.z * rsqrtf(fmaxf(q4.z * invN - mz * mz, 0.f) + BN_EPS);
    float scw = g4.w * rsqrtf(fmaxf(q4.w * invN - mw * mw, 0.f) + BN_EPS);
    float shx = be.x - mx * scx, shy = be.y - my * scy;
    float shz = be.z - mz * scz, shw = be.w - mw * scw;

    for (int idx = tid; idx < NN * (D / 4); idx += stride) {
        float4 a = ((const float4*)out)[idx];
        a.x = a.x * scx + shx;
        a.y = a.y * scy + shy;
        a.z = a.z * scz + shz;
        a.w = a.w * scw + shw;
        ((float4*)out)[idx] = a;
    }
}

extern "C" void kernel_launch(void* const* d_in, const int* in_sizes, int n_in,
                              void* d_out, int out_size, void* d_ws, size_t ws_size,
                              hipStream_t stream) {
    const float* x     = (const float*)d_in[0];
    const int*   ei    = (const int*)d_in[1];  // harness passes integer inputs as int32
    const float* W     = (const float*)d_in[2];
    const float* b     = (const float*)d_in[3];
    const float* gamma = (const float*)d_in[4];
    const float* beta  = (const float*)d_in[5];
    float*       out   = (float*)d_out;

    char* ws = (char*)d_ws;
    float*    dinv = (float*)ws;              // 400,000 B
    unsigned* deg  = (unsigned*)(ws + 400000);// 400,000 B
    float*    sums = (float*)(ws + 800000);   //   1,024 B

    k_init<<<(NN + 255) / 256, 256, 0, stream>>>(deg, sums);
    k_deg<<<(NE + 255) / 256, 256, 0, stream>>>(ei, deg);
    k_dinv<<<(NN + 255) / 256, 256, 0, stream>>>(deg, dinv);
    k_selfagg<<<NN * (D / 4) / 256, 256, 0, stream>>>(x, dinv, out);
    k_edges<<<4096, 256, 0, stream>>>(ei, x, dinv, out);
    k_gemmip<<<512, 256, 0, stream>>>(out, W, b);
    k_stats<<<512, 256, 0, stream>>>(out, sums);
    k_apply<<<2048, 256, 0, stream>>>(out, gamma, beta, sums);
}

// Round 3
// 499.761 us; speedup vs baseline: 3.0916x; 3.0916x over previous
//
#include <hip/hip_runtime.h>
#include <math.h>

#define NN 100000
#define NE 1600000
#define D 128
#define BN_EPS 1e-5f
#define NCHUNK 391  // ceil(NN/256)

// ws layout (bytes):
// dinv   [0,        400000)
// deg    [400000,   800000)
// sums   [800000,   801024)
// cnt    [801024,  1201024)   in-degree per target (excl. self)
// off    [1201024, 1601024)   CSR exclusive offsets
// cursor [1601024, 2001024)   scatter cursors (destroyed)
// part   [2001024, 2003072)   scan partials
// edata  [2003072, 14803072)  (src,norm) per edge, 8 B each

// ---------------- kernel 1: init deg=1, cnt=0, sums=0 ---------------------------
__global__ void k_init(unsigned* __restrict__ deg, unsigned* __restrict__ cnt,
                       float* __restrict__ sums) {
    int i = blockIdx.x * blockDim.x + threadIdx.x;
    if (i < NN) { deg[i] = 1u; cnt[i] = 0u; }
    if (i < 256) sums[i] = 0.f;
}

// ------- kernel 2: out-degree over row (for norm) + in-degree over col (CSR) ----
__global__ void k_deg(const int* __restrict__ ei, unsigned* __restrict__ deg,
                      unsigned* __restrict__ cnt) {
    int e = blockIdx.x * blockDim.x + threadIdx.x;
    if (e >= NE) return;
    int r = ei[e];
    int c = ei[NE + e];
    if (r != c) {
        atomicAdd(&deg[r], 1u);
        atomicAdd(&cnt[c], 1u);
    }
}

// ---------------- kernel 3: dinv = rsqrt(deg) -----------------------------------
__global__ void k_dinv(const unsigned* __restrict__ deg, float* __restrict__ dinv) {
    int i = blockIdx.x * blockDim.x + threadIdx.x;
    if (i < NN) dinv[i] = rsqrtf((float)deg[i]);
}

// ---------------- scan step 1: per-chunk sums -----------------------------------
__global__ __launch_bounds__(256) void k_scan1(const unsigned* __restrict__ cnt,
                                               unsigned* __restrict__ part) {
    __shared__ unsigned s[256];
    int i = blockIdx.x * 256 + threadIdx.x;
    unsigned v = (i < NN) ? cnt[i] : 0u;
    s[threadIdx.x] = v;
    __syncthreads();
    for (int o = 128; o > 0; o >>= 1) {
        if (threadIdx.x < o) s[threadIdx.x] += s[threadIdx.x + o];
        __syncthreads();
    }
    if (threadIdx.x == 0) part[blockIdx.x] = s[0];
}

// ---------------- scan step 2: exclusive scan of partials (1 block) -------------
__global__ __launch_bounds__(512) void k_scan2(unsigned* __restrict__ part) {
    __shared__ unsigned s[512];
    int t = threadIdx.x;
    unsigned v = (t < NCHUNK) ? part[t] : 0u;
    s[t] = v;
    __syncthreads();
    for (int o = 1; o < 512; o <<= 1) {
        unsigned add = (t >= o) ? s[t - o] : 0u;
        __syncthreads();
        s[t] += add;
        __syncthreads();
    }
    if (t < NCHUNK) part[t] = s[t] - v;  // exclusive
}

// ---------------- scan step 3: per-chunk exclusive offsets + cursor copy --------
__global__ __launch_bounds__(256) void k_scan3(const unsigned* __restrict__ cnt,
                                               const unsigned* __restrict__ part,
                                               unsigned* __restrict__ off,
                                               unsigned* __restrict__ cursor) {
    __shared__ unsigned s[256];
    int i = blockIdx.x * 256 + threadIdx.x;
    int t = threadIdx.x;
    unsigned v = (i < NN) ? cnt[i] : 0u;
    s[t] = v;
    __syncthreads();
    for (int o = 1; o < 256; o <<= 1) {
        unsigned add = (t >= o) ? s[t - o] : 0u;
        __syncthreads();
        s[t] += add;
        __syncthreads();
    }
    if (i < NN) {
        unsigned e = part[blockIdx.x] + s[t] - v;  // exclusive
        off[i] = e;
        cursor[i] = e;
    }
}

// ---------------- kernel 4: scatter (src, norm) into CSR buckets ----------------
__global__ void k_scatter(const int* __restrict__ ei, const float* __restrict__ dinv,
                          unsigned* __restrict__ cursor, int2* __restrict__ edata) {
    int e = blockIdx.x * blockDim.x + threadIdx.x;
    if (e >= NE) return;
    int r = ei[e];
    int c = ei[NE + e];
    if (r == c) return;  // ew = 0 for raw self-loop edges
    float w = dinv[r] * dinv[c];
    unsigned pos = atomicAdd(&cursor[c], 1u);
    edata[pos] = make_int2(r, __float_as_int(w));
}

// -------- kernel 5: per-node gather-accumulate + self-loop term → out -----------
__global__ __launch_bounds__(256) void k_gather(const float* __restrict__ x,
                                                const float* __restrict__ dinv,
                                                const unsigned* __restrict__ off,
                                                const unsigned* __restrict__ cnt,
                                                const int2* __restrict__ edata,
                                                float* __restrict__ out) {
    const int lane = threadIdx.x & 63;
    const int wave = threadIdx.x >> 6;
    const int c = blockIdx.x * 4 + wave;
    if (c >= NN) return;

    float d = dinv[c];
    float s = d * d;
    float2 acc = *(const float2*)&x[c * D + 2 * lane];
    acc.x *= s; acc.y *= s;

    const int base = off[c];
    const int n = cnt[c];
    int i = 0;
    for (; i + 2 <= n; i += 2) {
        int2 e0 = edata[base + i];
        int2 e1 = edata[base + i + 1];
        float2 x0 = *(const float2*)&x[e0.x * D + 2 * lane];
        float2 x1 = *(const float2*)&x[e1.x * D + 2 * lane];
        float w0 = __int_as_float(e0.y);
        float w1 = __int_as_float(e1.y);
        acc.x = fmaf(w0, x0.x, acc.x); acc.y = fmaf(w0, x0.y, acc.y);
        acc.x = fmaf(w1, x1.x, acc.x); acc.y = fmaf(w1, x1.y, acc.y);
    }
    if (i < n) {
        int2 e0 = edata[base + i];
        float2 x0 = *(const float2*)&x[e0.x * D + 2 * lane];
        float w0 = __int_as_float(e0.y);
        acc.x = fmaf(w0, x0.x, acc.x); acc.y = fmaf(w0, x0.y, acc.y);
    }
    *(float2*)&out[c * D + 2 * lane] = acc;
}

// ------------- kernel 6: in-place out_row = relu(out_row @ W + b) ---------------
__global__ __launch_bounds__(256) void k_gemmip(float* __restrict__ out,
                                                const float* __restrict__ W,
                                                const float* __restrict__ b) {
    __shared__ float Wl[D * D];  // 64 KB
    for (int t = threadIdx.x; t < D * D / 4; t += 256)
        ((float4*)Wl)[t] = ((const float4*)W)[t];
    __syncthreads();

    const int lane = threadIdx.x & 63;
    const int wave = threadIdx.x >> 6;
    const float blo = b[lane], bhi = b[lane + 64];
    const int gw = blockIdx.x * 4 + wave;
    const int nw = gridDim.x * 4;

    for (int tile = gw; tile < NN / 4; tile += nw) {
        float* r0 = out + (tile * 4 + 0) * D;
        float* r1 = out + (tile * 4 + 1) * D;
        float* r2 = out + (tile * 4 + 2) * D;
        float* r3 = out + (tile * 4 + 3) * D;
        float a0l = 0.f, a0h = 0.f, a1l = 0.f, a1h = 0.f;
        float a2l = 0.f, a2h = 0.f, a3l = 0.f, a3h = 0.f;
        for (int k4 = 0; k4 < D; k4 += 4) {
            float4 x0 = *(const float4*)&r0[k4];
            float4 x1 = *(const float4*)&r1[k4];
            float4 x2 = *(const float4*)&r2[k4];
            float4 x3 = *(const float4*)&r3[k4];
            float xa0[4] = {x0.x, x0.y, x0.z, x0.w};
            float xa1[4] = {x1.x, x1.y, x1.z, x1.w};
            float xa2[4] = {x2.x, x2.y, x2.z, x2.w};
            float xa3[4] = {x3.x, x3.y, x3.z, x3.w};
            #pragma unroll
            for (int j = 0; j < 4; ++j) {
                float wlo = Wl[(k4 + j) * D + lane];
                float whi = Wl[(k4 + j) * D + 64 + lane];
                a0l = fmaf(xa0[j], wlo, a0l); a0h = fmaf(xa0[j], whi, a0h);
                a1l = fmaf(xa1[j], wlo, a1l); a1h = fmaf(xa1[j], whi, a1h);
                a2l = fmaf(xa2[j], wlo, a2l); a2h = fmaf(xa2[j], whi, a2h);
                a3l = fmaf(xa3[j], wlo, a3l); a3h = fmaf(xa3[j], whi, a3h);
            }
        }
        r0[lane] = fmaxf(a0l + blo, 0.f); r0[lane + 64] = fmaxf(a0h + bhi, 0.f);
        r1[lane] = fmaxf(a1l + blo, 0.f); r1[lane + 64] = fmaxf(a1h + bhi, 0.f);
        r2[lane] = fmaxf(a2l + blo, 0.f); r2[lane + 64] = fmaxf(a2h + bhi, 0.f);
        r3[lane] = fmaxf(a3l + blo, 0.f); r3[lane + 64] = fmaxf(a3h + bhi, 0.f);
    }
}

// ------------- kernel 7: BN stats (sum, sumsq per channel) ----------------------
__global__ __launch_bounds__(256) void k_stats(const float* __restrict__ out,
                                               float* __restrict__ sums) {
    const int c  = threadIdx.x & 127;
    const int rg = threadIdx.x >> 7;
    float s = 0.f, s2 = 0.f;
    for (int row = blockIdx.x * 2 + rg; row < NN; row += gridDim.x * 2) {
        float v = out[row * D + c];
        s += v;
        s2 = fmaf(v, v, s2);
    }
    __shared__ float r1[128], r2[128];
    if (rg == 1) { r1[c] = s; r2[c] = s2; }
    __syncthreads();
    if (rg == 0) {
        s += r1[c];
        s2 += r2[c];
        unsafeAtomicAdd(&sums[c], s);
        unsafeAtomicAdd(&sums[128 + c], s2);
    }
}

// ------------- kernel 8: out = out * scale + shift  (BN affine) -----------------
__global__ __launch_bounds__(256) void k_apply(float* __restrict__ out,
                                               const float* __restrict__ gamma,
                                               const float* __restrict__ beta,
                                               const float* __restrict__ sums) {
    const float invN = 1.f / (float)NN;
    const int tid = blockIdx.x * blockDim.x + threadIdx.x;
    const int stride = gridDim.x * blockDim.x;  // multiple of 32 -> channel-stable
    const int c4 = (tid & 31) * 4;

    float4 g4 = *(const float4*)&gamma[c4];
    float4 be = *(const float4*)&beta[c4];
    float4 s4 = *(const float4*)&sums[c4];
    float4 q4 = *(const float4*)&sums[128 + c4];

    float mx = s4.x * invN, my = s4.y * invN, mz = s4.z * invN, mw = s4.w * invN;
    float scx = g4.x * rsqrtf(fmaxf(q4.x * invN - mx * mx, 0.f) + BN_EPS);
    float scy = g4.y * rsqrtf(fmaxf(q4.y * invN - my * my, 0.f) + BN_EPS);
    float scz = g4.z * rsqrtf(fmaxf(q4.z * invN - mz * mz, 0.f) + BN_EPS);
    float scw = g4.w * rsqrtf(fmaxf(q4.w * invN - mw * mw, 0.f) + BN_EPS);
    float shx = be.x - mx * scx, shy = be.y - my * scy;
    float shz = be.z - mz * scz, shw = be.w - mw * scw;

    for (int idx = tid; idx < NN * (D / 4); idx += stride) {
        float4 a = ((const float4*)out)[idx];
        a.x = a.x * scx + shx;
        a.y = a.y * scy + shy;
        a.z = a.z * scz + shz;
        a.w = a.w * scw + shw;
        ((float4*)out)[idx] = a;
    }
}

extern "C" void kernel_launch(void* const* d_in, const int* in_sizes, int n_in,
                              void* d_out, int out_size, void* d_ws, size_t ws_size,
                              hipStream_t stream) {
    const float* x     = (const float*)d_in[0];
    const int*   ei    = (const int*)d_in[1];
    const float* W     = (const float*)d_in[2];
    const float* b     = (const float*)d_in[3];
    const float* gamma = (const float*)d_in[4];
    const float* beta  = (const float*)d_in[5];
    float*       out   = (float*)d_out;

    char* ws = (char*)d_ws;
    float*    dinv   = (float*)ws;
    unsigned* deg    = (unsigned*)(ws + 400000);
    float*    sums   = (float*)(ws + 800000);
    unsigned* cnt    = (unsigned*)(ws + 801024);
    unsigned* off    = (unsigned*)(ws + 1201024);
    unsigned* cursor = (unsigned*)(ws + 1601024);
    unsigned* part   = (unsigned*)(ws + 2001024);
    int2*     edata  = (int2*)(ws + 2003072);

    k_init<<<NCHUNK, 256, 0, stream>>>(deg, cnt, sums);
    k_deg<<<(NE + 255) / 256, 256, 0, stream>>>(ei, deg, cnt);
    k_dinv<<<NCHUNK, 256, 0, stream>>>(deg, dinv);
    k_scan1<<<NCHUNK, 256, 0, stream>>>(cnt, part);
    k_scan2<<<1, 512, 0, stream>>>(part);
    k_scan3<<<NCHUNK, 256, 0, stream>>>(cnt, part, off, cursor);
    k_scatter<<<(NE + 255) / 256, 256, 0, stream>>>(ei, dinv, cursor, edata);
    k_gather<<<(NN + 3) / 4, 256, 0, stream>>>(x, dinv, off, cnt, edata, out);
    k_gemmip<<<512, 256, 0, stream>>>(out, W, b);
    k_stats<<<512, 256, 0, stream>>>(out, sums);
    k_apply<<<2048, 256, 0, stream>>>(out, gamma, beta, sums);
}

// Round 4
// 431.832 us; speedup vs baseline: 3.5780x; 1.1573x over previous
//
#include <hip/hip_runtime.h>
#include <math.h>

#define NN 100000
#define NE 1600000
#define D 128
#define BN_EPS 1e-5f
#define NCHUNK 391  // ceil(NN/256)

typedef __attribute__((ext_vector_type(8))) short short8;
typedef __attribute__((ext_vector_type(4))) float f32x4;

// ws layout (bytes):
// dinv   [0,        400000)
// deg    [400000,   800000)
// sums   [800000,   801024)
// cnt    [801024,  1201024)
// off    [1201024, 1601024)
// cursor [1601024, 2001024)
// part   [2001024, 2003072)
// esrc   [2003072,  8403072)   src per CSR slot, 4 B
// xh     [8403072, 34003072)   x in bf16, packed 2/uint, [NN][64] uints
// Wht    [34003072,34035840)   W^T in bf16, [c][k] row-major, 32 KB

__device__ __forceinline__ unsigned bf_rne(float f) {
    unsigned u = __float_as_uint(f);
    return (u + 0x7fffu + ((u >> 16) & 1u)) >> 16;
}
__device__ __forceinline__ unsigned pk2(float lo, float hi) {
    return bf_rne(lo) | (bf_rne(hi) << 16);
}

// ---------------- kernel 1: init deg=1, cnt=0, sums=0 ---------------------------
__global__ void k_init(unsigned* __restrict__ deg, unsigned* __restrict__ cnt,
                       float* __restrict__ sums) {
    int i = blockIdx.x * blockDim.x + threadIdx.x;
    if (i < NN) { deg[i] = 1u; cnt[i] = 0u; }
    if (i < 256) sums[i] = 0.f;
}

// ---------------- kernel 2: x -> bf16 packed ------------------------------------
__global__ void k_cvt(const float* __restrict__ x, unsigned* __restrict__ xh) {
    int i = blockIdx.x * blockDim.x + threadIdx.x;
    if (i < NN * 64) {
        float2 v = ((const float2*)x)[i];
        xh[i] = pk2(v.x, v.y);
    }
}

// ---------------- kernel 2b: W[k][c] -> Wht[c][k] bf16 --------------------------
__global__ void k_cvtw(const float* __restrict__ W, unsigned short* __restrict__ Wht) {
    int i = blockIdx.x * blockDim.x + threadIdx.x;  // i = k*128 + c
    if (i < D * D) {
        int k = i >> 7, c = i & 127;
        Wht[c * D + k] = (unsigned short)bf_rne(W[i]);
    }
}

// ------- kernel 3: out-degree over row (norm) + in-degree over col (CSR) --------
__global__ void k_deg(const int* __restrict__ ei, unsigned* __restrict__ deg,
                      unsigned* __restrict__ cnt) {
    int e = blockIdx.x * blockDim.x + threadIdx.x;
    if (e >= NE) return;
    int r = ei[e];
    int c = ei[NE + e];
    if (r != c) {
        atomicAdd(&deg[r], 1u);
        atomicAdd(&cnt[c], 1u);
    }
}

// ---------------- kernel 4: dinv = rsqrt(deg) -----------------------------------
__global__ void k_dinv(const unsigned* __restrict__ deg, float* __restrict__ dinv) {
    int i = blockIdx.x * blockDim.x + threadIdx.x;
    if (i < NN) dinv[i] = rsqrtf((float)deg[i]);
}

// ---------------- scan step 1: per-chunk sums -----------------------------------
__global__ __launch_bounds__(256) void k_scan1(const unsigned* __restrict__ cnt,
                                               unsigned* __restrict__ part) {
    __shared__ unsigned s[256];
    int i = blockIdx.x * 256 + threadIdx.x;
    unsigned v = (i < NN) ? cnt[i] : 0u;
    s[threadIdx.x] = v;
    __syncthreads();
    for (int o = 128; o > 0; o >>= 1) {
        if (threadIdx.x < o) s[threadIdx.x] += s[threadIdx.x + o];
        __syncthreads();
    }
    if (threadIdx.x == 0) part[blockIdx.x] = s[0];
}

// ---------------- scan step 2: exclusive scan of partials (1 block) -------------
__global__ __launch_bounds__(512) void k_scan2(unsigned* __restrict__ part) {
    __shared__ unsigned s[512];
    int t = threadIdx.x;
    unsigned v = (t < NCHUNK) ? part[t] : 0u;
    s[t] = v;
    __syncthreads();
    for (int o = 1; o < 512; o <<= 1) {
        unsigned add = (t >= o) ? s[t - o] : 0u;
        __syncthreads();
        s[t] += add;
        __syncthreads();
    }
    if (t < NCHUNK) part[t] = s[t] - v;  // exclusive
}

// ---------------- scan step 3: per-chunk exclusive offsets + cursor copy --------
__global__ __launch_bounds__(256) void k_scan3(const unsigned* __restrict__ cnt,
                                               const unsigned* __restrict__ part,
                                               unsigned* __restrict__ off,
                                               unsigned* __restrict__ cursor) {
    __shared__ unsigned s[256];
    int i = blockIdx.x * 256 + threadIdx.x;
    int t = threadIdx.x;
    unsigned v = (i < NN) ? cnt[i] : 0u;
    s[t] = v;
    __syncthreads();
    for (int o = 1; o < 256; o <<= 1) {
        unsigned add = (t >= o) ? s[t - o] : 0u;
        __syncthreads();
        s[t] += add;
        __syncthreads();
    }
    if (i < NN) {
        unsigned e = part[blockIdx.x] + s[t] - v;  // exclusive
        off[i] = e;
        cursor[i] = e;
    }
}

// ---------------- kernel 5: scatter src into CSR buckets ------------------------
__global__ void k_scatter(const int* __restrict__ ei, unsigned* __restrict__ cursor,
                          int* __restrict__ esrc) {
    int e = blockIdx.x * blockDim.x + threadIdx.x;
    if (e >= NE) return;
    int r = ei[e];
    int c = ei[NE + e];
    if (r == c) return;  // ew = 0 for raw self-loop edges
    unsigned pos = atomicAdd(&cursor[c], 1u);
    esrc[pos] = r;
}

// -------- kernel 6: gather bf16 rows: out_c = dc*(dc*x_c + sum dr*x_r) ----------
__global__ __launch_bounds__(256) void k_gather(const unsigned* __restrict__ xh,
                                                const float* __restrict__ dinv,
                                                const unsigned* __restrict__ off,
                                                const unsigned* __restrict__ cnt,
                                                const int* __restrict__ esrc,
                                                float* __restrict__ out) {
    const int lane = threadIdx.x & 63;
    const int wave = threadIdx.x >> 6;
    const int c = blockIdx.x * 4 + wave;
    if (c >= NN) return;

    const float dc = dinv[c];
    unsigned xc = xh[c * 64 + lane];
    float al = dc * __uint_as_float(xc << 16);
    float ah = dc * __uint_as_float(xc & 0xffff0000u);

    const int base = off[c];
    const int n = cnt[c];
    int i = 0;
    for (; i + 4 <= n; i += 4) {
        int s0 = esrc[base + i], s1 = esrc[base + i + 1];
        int s2 = esrc[base + i + 2], s3 = esrc[base + i + 3];
        float w0 = dinv[s0], w1 = dinv[s1], w2 = dinv[s2], w3 = dinv[s3];
        unsigned p0 = xh[s0 * 64 + lane], p1 = xh[s1 * 64 + lane];
        unsigned p2 = xh[s2 * 64 + lane], p3 = xh[s3 * 64 + lane];
        al = fmaf(w0, __uint_as_float(p0 << 16), al);
        ah = fmaf(w0, __uint_as_float(p0 & 0xffff0000u), ah);
        al = fmaf(w1, __uint_as_float(p1 << 16), al);
        ah = fmaf(w1, __uint_as_float(p1 & 0xffff0000u), ah);
        al = fmaf(w2, __uint_as_float(p2 << 16), al);
        ah = fmaf(w2, __uint_as_float(p2 & 0xffff0000u), ah);
        al = fmaf(w3, __uint_as_float(p3 << 16), al);
        ah = fmaf(w3, __uint_as_float(p3 & 0xffff0000u), ah);
    }
    for (; i < n; ++i) {
        int s0 = esrc[base + i];
        float w0 = dinv[s0];
        unsigned p0 = xh[s0 * 64 + lane];
        al = fmaf(w0, __uint_as_float(p0 << 16), al);
        ah = fmaf(w0, __uint_as_float(p0 & 0xffff0000u), ah);
    }
    al *= dc;
    ah *= dc;
    *(float2*)&out[c * D + 2 * lane] = make_float2(al, ah);
}

// -------- kernel 7: in-place MFMA GEMM: out_tile = relu(out_tile @ W + b) -------
// One wave owns one 16-row tile: all A-loads precede the tile's stores.
// A-frag (16x16x32 bf16): lane l holds A[row=l&15][k=(l>>4)*8+i], i=0..7
// B-frag:                 lane l holds B[k=(l>>4)*8+i][col=l&15]  (= Wht[col][k])
// C/D  :                  lane l reg r -> row=(l>>4)*4+r, col=l&15   [m89]
__global__ __launch_bounds__(256, 1) void k_gemm(float* __restrict__ out,
                                                 const unsigned short* __restrict__ Wht,
                                                 const float* __restrict__ b) {
    const int lane = threadIdx.x & 63;
    const int wv = threadIdx.x >> 6;
    const int l15 = lane & 15, l4 = lane >> 4;

    short8 bfr[8][4];
    #pragma unroll
    for (int n = 0; n < 8; ++n)
        #pragma unroll
        for (int kk = 0; kk < 4; ++kk)
            bfr[n][kk] = *(const short8*)(Wht + (n * 16 + l15) * D + kk * 32 + l4 * 8);

    float bias8[8];
    #pragma unroll
    for (int n = 0; n < 8; ++n) bias8[n] = b[n * 16 + l15];

    const int gw = blockIdx.x * 4 + wv;
    #pragma unroll
    for (int t = 0; t < 2; ++t) {
        const int tile = gw * 2 + t;
        if (tile < NN / 16) {
            const int row0 = tile * 16;
            short8 af[4];
            #pragma unroll
            for (int kk = 0; kk < 4; ++kk) {
                const float* ar = out + (row0 + l15) * D + kk * 32 + l4 * 8;
                float4 a0 = *(const float4*)ar;
                float4 a1 = *(const float4*)(ar + 4);
                union { short8 s; unsigned u[4]; } cv;
                cv.u[0] = pk2(a0.x, a0.y);
                cv.u[1] = pk2(a0.z, a0.w);
                cv.u[2] = pk2(a1.x, a1.y);
                cv.u[3] = pk2(a1.z, a1.w);
                af[kk] = cv.s;
            }
            f32x4 acc[8];
            #pragma unroll
            for (int n = 0; n < 8; ++n) acc[n] = (f32x4){0.f, 0.f, 0.f, 0.f};
            #pragma unroll
            for (int n = 0; n < 8; ++n)
                #pragma unroll
                for (int kk = 0; kk < 4; ++kk)
                    acc[n] = __builtin_amdgcn_mfma_f32_16x16x32_bf16(af[kk], bfr[n][kk],
                                                                     acc[n], 0, 0, 0);
            #pragma unroll
            for (int n = 0; n < 8; ++n)
                #pragma unroll
                for (int r = 0; r < 4; ++r) {
                    int row = row0 + l4 * 4 + r;
                    out[row * D + n * 16 + l15] = fmaxf(acc[n][r] + bias8[n], 0.f);
                }
        }
    }
}

// ------------- kernel 8: BN stats (sum, sumsq per channel) ----------------------
__global__ __launch_bounds__(256) void k_stats(const float* __restrict__ out,
                                               float* __restrict__ sums) {
    const int c  = threadIdx.x & 127;
    const int rg = threadIdx.x >> 7;
    float s = 0.f, s2 = 0.f;
    for (int row = blockIdx.x * 2 + rg; row < NN; row += gridDim.x * 2) {
        float v = out[row * D + c];
        s += v;
        s2 = fmaf(v, v, s2);
    }
    __shared__ float r1[128], r2[128];
    if (rg == 1) { r1[c] = s; r2[c] = s2; }
    __syncthreads();
    if (rg == 0) {
        s += r1[c];
        s2 += r2[c];
        unsafeAtomicAdd(&sums[c], s);
        unsafeAtomicAdd(&sums[128 + c], s2);
    }
}

// ------------- kernel 9: out = out * scale + shift  (BN affine) -----------------
__global__ __launch_bounds__(256) void k_apply(float* __restrict__ out,
                                               const float* __restrict__ gamma,
                                               const float* __restrict__ beta,
                                               const float* __restrict__ sums) {
    const float invN = 1.f / (float)NN;
    const int tid = blockIdx.x * blockDim.x + threadIdx.x;
    const int stride = gridDim.x * blockDim.x;
    const int c4 = (tid & 31) * 4;

    float4 g4 = *(const float4*)&gamma[c4];
    float4 be = *(const float4*)&beta[c4];
    float4 s4 = *(const float4*)&sums[c4];
    float4 q4 = *(const float4*)&sums[128 + c4];

    float mx = s4.x * invN, my = s4.y * invN, mz = s4.z * invN, mw = s4.w * invN;
    float scx = g4.x * rsqrtf(fmaxf(q4.x * invN - mx * mx, 0.f) + BN_EPS);
    float scy = g4.y * rsqrtf(fmaxf(q4.y * invN - my * my, 0.f) + BN_EPS);
    float scz = g4.z * rsqrtf(fmaxf(q4.z * invN - mz * mz, 0.f) + BN_EPS);
    float scw = g4.w * rsqrtf(fmaxf(q4.w * invN - mw * mw, 0.f) + BN_EPS);
    float shx = be.x - mx * scx, shy = be.y - my * scy;
    float shz = be.z - mz * scz, shw = be.w - mw * scw;

    for (int idx = tid; idx < NN * (D / 4); idx += stride) {
        float4 a = ((const float4*)out)[idx];
        a.x = a.x * scx + shx;
        a.y = a.y * scy + shy;
        a.z = a.z * scz + shz;
        a.w = a.w * scw + shw;
        ((float4*)out)[idx] = a;
    }
}

extern "C" void kernel_launch(void* const* d_in, const int* in_sizes, int n_in,
                              void* d_out, int out_size, void* d_ws, size_t ws_size,
                              hipStream_t stream) {
    const float* x     = (const float*)d_in[0];
    const int*   ei    = (const int*)d_in[1];
    const float* W     = (const float*)d_in[2];
    const float* b     = (const float*)d_in[3];
    const float* gamma = (const float*)d_in[4];
    const float* beta  = (const float*)d_in[5];
    float*       out   = (float*)d_out;

    char* ws = (char*)d_ws;
    float*          dinv   = (float*)ws;
    unsigned*       deg    = (unsigned*)(ws + 400000);
    float*          sums   = (float*)(ws + 800000);
    unsigned*       cnt    = (unsigned*)(ws + 801024);
    unsigned*       off    = (unsigned*)(ws + 1201024);
    unsigned*       cursor = (unsigned*)(ws + 1601024);
    unsigned*       part   = (unsigned*)(ws + 2001024);
    int*            esrc   = (int*)(ws + 2003072);
    unsigned*       xh     = (unsigned*)(ws + 8403072);
    unsigned short* Wht    = (unsigned short*)(ws + 34003072);

    k_init<<<NCHUNK, 256, 0, stream>>>(deg, cnt, sums);
    k_cvt<<<25000, 256, 0, stream>>>(x, xh);
    k_cvtw<<<64, 256, 0, stream>>>(W, Wht);
    k_deg<<<(NE + 255) / 256, 256, 0, stream>>>(ei, deg, cnt);
    k_dinv<<<NCHUNK, 256, 0, stream>>>(deg, dinv);
    k_scan1<<<NCHUNK, 256, 0, stream>>>(cnt, part);
    k_scan2<<<1, 512, 0, stream>>>(part);
    k_scan3<<<NCHUNK, 256, 0, stream>>>(cnt, part, off, cursor);
    k_scatter<<<(NE + 255) / 256, 256, 0, stream>>>(ei, cursor, esrc);
    k_gather<<<25000, 256, 0, stream>>>(xh, dinv, off, cnt, esrc, out);
    k_gemm<<<782, 256, 0, stream>>>(out, Wht, b);
    k_stats<<<512, 256, 0, stream>>>(out, sums);
    k_apply<<<2048, 256, 0, stream>>>(out, gamma, beta, sums);
}

// Round 6
// 396.475 us; speedup vs baseline: 3.8970x; 1.0892x over previous
//
#include <hip/hip_runtime.h>
#include <math.h>

#define NN 100000
#define NE 1600000
#define D 128
#define BN_EPS 1e-5f
#define NCHUNK 391   // ceil(NN/256)
#define GSZ 12500    // NN / 8 (one node range per XCD group)
#define ECH 2048     // edges per chunk for partitioned edge kernels
#define NECH 782     // ceil(NE/ECH)

typedef __attribute__((ext_vector_type(8))) short short8;
typedef __attribute__((ext_vector_type(4))) float f32x4;
typedef __attribute__((ext_vector_type(2))) float f32x2;

// ws layout (bytes):
// dinv   [0,        400000)
// deg    [400000,   800000)
// sums   [800000,   801024)
// cnt    [801024,  1201024)
// off    [1201024, 1601024)
// cursor [1601024, 2001024)
// part   [2001024, 2003072)
// esrc   [2003072,  8403072)   src per CSR slot, 4 B
// xh     [8403072, 34003072)   x in bf16, packed 2/uint, [NN][64] uints
// Wht    [34003072,34035840)   W^T in bf16, [c][k] row-major, 32 KB

__device__ __forceinline__ unsigned bf_rne(float f) {
    unsigned u = __float_as_uint(f);
    return (u + 0x7fffu + ((u >> 16) & 1u)) >> 16;
}
__device__ __forceinline__ unsigned pk2(float lo, float hi) {
    return bf_rne(lo) | (bf_rne(hi) << 16);
}

// ---------------- kernel 1: init deg=1, cnt=0, sums=0 ---------------------------
__global__ void k_init(unsigned* __restrict__ deg, unsigned* __restrict__ cnt,
                       float* __restrict__ sums) {
    int i = blockIdx.x * blockDim.x + threadIdx.x;
    if (i < NN) { deg[i] = 1u; cnt[i] = 0u; }
    if (i < 256) sums[i] = 0.f;
}

// ---------------- kernel 2: x -> bf16 packed (nt reads: don't pollute L2) -------
__global__ void k_cvt(const float* __restrict__ x, unsigned* __restrict__ xh) {
    int i = blockIdx.x * blockDim.x + threadIdx.x;
    if (i < NN * 64) {
        f32x2 v = __builtin_nontemporal_load((const f32x2*)x + i);
        xh[i] = pk2(v.x, v.y);
    }
}

// ---------------- kernel 2b: W[k][c] -> Wht[c][k] bf16 --------------------------
__global__ void k_cvtw(const float* __restrict__ W, unsigned short* __restrict__ Wht) {
    int i = blockIdx.x * blockDim.x + threadIdx.x;  // i = k*128 + c
    if (i < D * D) {
        int k = i >> 7, c = i & 127;
        Wht[c * D + k] = (unsigned short)bf_rne(W[i]);
    }
}

// ------- kernel 3: XCD-partitioned histograms: deg over r, cnt over c -----------
// blockIdx%8 tracks the XCD round-robin; group g owns nodes [g*GSZ,(g+1)*GSZ).
// Each group's 50 KB histogram slice stays in its local L2 -> fast atomics, no
// partial-line HBM writebacks. Edge stream read 8x, non-temporally.
__global__ __launch_bounds__(256) void k_deg(const int* __restrict__ ei,
                                             unsigned* __restrict__ deg,
                                             unsigned* __restrict__ cnt) {
    const int g = blockIdx.x & 7;
    const int chunk = blockIdx.x >> 3;
    const int lo = g * GSZ, hi = lo + GSZ;
    const int end = (chunk * ECH + ECH < NE) ? chunk * ECH + ECH : NE;
    for (int i = chunk * ECH + threadIdx.x; i < end; i += 256) {
        int r = __builtin_nontemporal_load(ei + i);
        int c = __builtin_nontemporal_load(ei + NE + i);
        if (r != c) {
            if (r >= lo && r < hi) atomicAdd(&deg[r], 1u);
            if (c >= lo && c < hi) atomicAdd(&cnt[c], 1u);
        }
    }
}

// ---------------- kernel 4: dinv = rsqrt(deg) -----------------------------------
__global__ void k_dinv(const unsigned* __restrict__ deg, float* __restrict__ dinv) {
    int i = blockIdx.x * blockDim.x + threadIdx.x;
    if (i < NN) dinv[i] = rsqrtf((float)deg[i]);
}

// ---------------- scan step 1: per-chunk sums -----------------------------------
__global__ __launch_bounds__(256) void k_scan1(const unsigned* __restrict__ cnt,
                                               unsigned* __restrict__ part) {
    __shared__ unsigned s[256];
    int i = blockIdx.x * 256 + threadIdx.x;
    unsigned v = (i < NN) ? cnt[i] : 0u;
    s[threadIdx.x] = v;
    __syncthreads();
    for (int o = 128; o > 0; o >>= 1) {
        if (threadIdx.x < o) s[threadIdx.x] += s[threadIdx.x + o];
        __syncthreads();
    }
    if (threadIdx.x == 0) part[blockIdx.x] = s[0];
}

// ---------------- scan step 2: exclusive scan of partials (1 block) -------------
__global__ __launch_bounds__(512) void k_scan2(unsigned* __restrict__ part) {
    __shared__ unsigned s[512];
    int t = threadIdx.x;
    unsigned v = (t < NCHUNK) ? part[t] : 0u;
    s[t] = v;
    __syncthreads();
    for (int o = 1; o < 512; o <<= 1) {
        unsigned add = (t >= o) ? s[t - o] : 0u;
        __syncthreads();
        s[t] += add;
        __syncthreads();
    }
    if (t < NCHUNK) part[t] = s[t] - v;  // exclusive
}

// ---------------- scan step 3: per-chunk exclusive offsets + cursor copy --------
__global__ __launch_bounds__(256) void k_scan3(const unsigned* __restrict__ cnt,
                                               const unsigned* __restrict__ part,
                                               unsigned* __restrict__ off,
                                               unsigned* __restrict__ cursor) {
    __shared__ unsigned s[256];
    int i = blockIdx.x * 256 + threadIdx.x;
    int t = threadIdx.x;
    unsigned v = (i < NN) ? cnt[i] : 0u;
    s[t] = v;
    __syncthreads();
    for (int o = 1; o < 256; o <<= 1) {
        unsigned add = (t >= o) ? s[t - o] : 0u;
        __syncthreads();
        s[t] += add;
        __syncthreads();
    }
    if (i < NN) {
        unsigned e = part[blockIdx.x] + s[t] - v;  // exclusive
        off[i] = e;
        cursor[i] = e;
    }
}

// ------- kernel 5: XCD-partitioned scatter of src into CSR buckets --------------
// Group g writes only slots off[g*GSZ]..off[(g+1)*GSZ) — one contiguous ~800 KB
// slice, L2-resident; cursor slice likewise. Kills partial-line writebacks.
__global__ __launch_bounds__(256) void k_scatter(const int* __restrict__ ei,
                                                 unsigned* __restrict__ cursor,
                                                 int* __restrict__ esrc) {
    const int g = blockIdx.x & 7;
    const int chunk = blockIdx.x >> 3;
    const int lo = g * GSZ, hi = lo + GSZ;
    const int end = (chunk * ECH + ECH < NE) ? chunk * ECH + ECH : NE;
    for (int i = chunk * ECH + threadIdx.x; i < end; i += 256) {
        int r = __builtin_nontemporal_load(ei + i);
        int c = __builtin_nontemporal_load(ei + NE + i);
        if (r == c) continue;
        if (c < lo || c >= hi) continue;
        unsigned pos = atomicAdd(&cursor[c], 1u);
        esrc[pos] = r;
    }
}

// -------- kernel 6: gather bf16 rows: out_c = dc*(dc*x_c + sum dr*x_r) ----------
__global__ __launch_bounds__(256) void k_gather(const unsigned* __restrict__ xh,
                                                const float* __restrict__ dinv,
                                                const unsigned* __restrict__ off,
                                                const unsigned* __restrict__ cnt,
                                                const int* __restrict__ esrc,
                                                float* __restrict__ out) {
    const int lane = threadIdx.x & 63;
    const int wave = threadIdx.x >> 6;
    const int c = blockIdx.x * 4 + wave;
    if (c >= NN) return;

    const float dc = dinv[c];
    unsigned xc = xh[c * 64 + lane];
    float al = dc * __uint_as_float(xc << 16);
    float ah = dc * __uint_as_float(xc & 0xffff0000u);

    const int base = off[c];
    const int n = cnt[c];
    int i = 0;
    for (; i + 4 <= n; i += 4) {
        int s0 = esrc[base + i], s1 = esrc[base + i + 1];
        int s2 = esrc[base + i + 2], s3 = esrc[base + i + 3];
        float w0 = dinv[s0], w1 = dinv[s1], w2 = dinv[s2], w3 = dinv[s3];
        unsigned p0 = xh[s0 * 64 + lane], p1 = xh[s1 * 64 + lane];
        unsigned p2 = xh[s2 * 64 + lane], p3 = xh[s3 * 64 + lane];
        al = fmaf(w0, __uint_as_float(p0 << 16), al);
        ah = fmaf(w0, __uint_as_float(p0 & 0xffff0000u), ah);
        al = fmaf(w1, __uint_as_float(p1 << 16), al);
        ah = fmaf(w1, __uint_as_float(p1 & 0xffff0000u), ah);
        al = fmaf(w2, __uint_as_float(p2 << 16), al);
        ah = fmaf(w2, __uint_as_float(p2 & 0xffff0000u), ah);
        al = fmaf(w3, __uint_as_float(p3 << 16), al);
        ah = fmaf(w3, __uint_as_float(p3 & 0xffff0000u), ah);
    }
    for (; i < n; ++i) {
        int s0 = esrc[base + i];
        float w0 = dinv[s0];
        unsigned p0 = xh[s0 * 64 + lane];
        al = fmaf(w0, __uint_as_float(p0 << 16), al);
        ah = fmaf(w0, __uint_as_float(p0 & 0xffff0000u), ah);
    }
    al *= dc;
    ah *= dc;
    *(float2*)&out[c * D + 2 * lane] = make_float2(al, ah);
}

// -------- kernel 7: in-place MFMA GEMM: out_tile = relu(out_tile @ W + b) -------
// One wave owns one 16-row tile: all A-loads precede the tile's stores.
__global__ __launch_bounds__(256, 1) void k_gemm(float* __restrict__ out,
                                                 const unsigned short* __restrict__ Wht,
                                                 const float* __restrict__ b) {
    const int lane = threadIdx.x & 63;
    const int wv = threadIdx.x >> 6;
    const int l15 = lane & 15, l4 = lane >> 4;

    short8 bfr[8][4];
    #pragma unroll
    for (int n = 0; n < 8; ++n)
        #pragma unroll
        for (int kk = 0; kk < 4; ++kk)
            bfr[n][kk] = *(const short8*)(Wht + (n * 16 + l15) * D + kk * 32 + l4 * 8);

    float bias8[8];
    #pragma unroll
    for (int n = 0; n < 8; ++n) bias8[n] = b[n * 16 + l15];

    const int gw = blockIdx.x * 4 + wv;
    #pragma unroll
    for (int t = 0; t < 2; ++t) {
        const int tile = gw * 2 + t;
        if (tile < NN / 16) {
            const int row0 = tile * 16;
            short8 af[4];
            #pragma unroll
            for (int kk = 0; kk < 4; ++kk) {
                const float* ar = out + (row0 + l15) * D + kk * 32 + l4 * 8;
                float4 a0 = *(const float4*)ar;
                float4 a1 = *(const float4*)(ar + 4);
                union { short8 s; unsigned u[4]; } cv;
                cv.u[0] = pk2(a0.x, a0.y);
                cv.u[1] = pk2(a0.z, a0.w);
                cv.u[2] = pk2(a1.x, a1.y);
                cv.u[3] = pk2(a1.z, a1.w);
                af[kk] = cv.s;
            }
            f32x4 acc[8];
            #pragma unroll
            for (int n = 0; n < 8; ++n) acc[n] = (f32x4){0.f, 0.f, 0.f, 0.f};
            #pragma unroll
            for (int n = 0; n < 8; ++n)
                #pragma unroll
                for (int kk = 0; kk < 4; ++kk)
                    acc[n] = __builtin_amdgcn_mfma_f32_16x16x32_bf16(af[kk], bfr[n][kk],
                                                                     acc[n], 0, 0, 0);
            #pragma unroll
            for (int n = 0; n < 8; ++n)
                #pragma unroll
                for (int r = 0; r < 4; ++r) {
                    int row = row0 + l4 * 4 + r;
                    out[row * D + n * 16 + l15] = fmaxf(acc[n][r] + bias8[n], 0.f);
                }
        }
    }
}

// ------------- kernel 8: BN stats (sum, sumsq per channel) ----------------------
__global__ __launch_bounds__(256) void k_stats(const float* __restrict__ out,
                                               float* __restrict__ sums) {
    const int c  = threadIdx.x & 127;
    const int rg = threadIdx.x >> 7;
    float s = 0.f, s2 = 0.f;
    for (int row = blockIdx.x * 2 + rg; row < NN; row += gridDim.x * 2) {
        float v = out[row * D + c];
        s += v;
        s2 = fmaf(v, v, s2);
    }
    __shared__ float r1[128], r2[128];
    if (rg == 1) { r1[c] = s; r2[c] = s2; }
    __syncthreads();
    if (rg == 0) {
        s += r1[c];
        s2 += r2[c];
        unsafeAtomicAdd(&sums[c], s);
        unsafeAtomicAdd(&sums[128 + c], s2);
    }
}

// ------------- kernel 9: out = out * scale + shift  (BN affine) -----------------
__global__ __launch_bounds__(256) void k_apply(float* __restrict__ out,
                                               const float* __restrict__ gamma,
                                               const float* __restrict__ beta,
                                               const float* __restrict__ sums) {
    const float invN = 1.f / (float)NN;
    const int tid = blockIdx.x * blockDim.x + threadIdx.x;
    const int stride = gridDim.x * blockDim.x;
    const int c4 = (tid & 31) * 4;

    float4 g4 = *(const float4*)&gamma[c4];
    float4 be = *(const float4*)&beta[c4];
    float4 s4 = *(const float4*)&sums[c4];
    float4 q4 = *(const float4*)&sums[128 + c4];

    float mx = s4.x * invN, my = s4.y * invN, mz = s4.z * invN, mw = s4.w * invN;
    float scx = g4.x * rsqrtf(fmaxf(q4.x * invN - mx * mx, 0.f) + BN_EPS);
    float scy = g4.y * rsqrtf(fmaxf(q4.y * invN - my * my, 0.f) + BN_EPS);
    float scz = g4.z * rsqrtf(fmaxf(q4.z * invN - mz * mz, 0.f) + BN_EPS);
    float scw = g4.w * rsqrtf(fmaxf(q4.w * invN - mw * mw, 0.f) + BN_EPS);
    float shx = be.x - mx * scx, shy = be.y - my * scy;
    float shz = be.z - mz * scz, shw = be.w - mw * scw;

    for (int idx = tid; idx < NN * (D / 4); idx += stride) {
        float4 a = ((const float4*)out)[idx];
        a.x = a.x * scx + shx;
        a.y = a.y * scy + shy;
        a.z = a.z * scz + shz;
        a.w = a.w * scw + shw;
        ((float4*)out)[idx] = a;
    }
}

extern "C" void kernel_launch(void* const* d_in, const int* in_sizes, int n_in,
                              void* d_out, int out_size, void* d_ws, size_t ws_size,
                              hipStream_t stream) {
    const float* x     = (const float*)d_in[0];
    const int*   ei    = (const int*)d_in[1];
    const float* W     = (const float*)d_in[2];
    const float* b     = (const float*)d_in[3];
    const float* gamma = (const float*)d_in[4];
    const float* beta  = (const float*)d_in[5];
    float*       out   = (float*)d_out;

    char* ws = (char*)d_ws;
    float*          dinv   = (float*)ws;
    unsigned*       deg    = (unsigned*)(ws + 400000);
    float*          sums   = (float*)(ws + 800000);
    unsigned*       cnt    = (unsigned*)(ws + 801024);
    unsigned*       off    = (unsigned*)(ws + 1201024);
    unsigned*       cursor = (unsigned*)(ws + 1601024);
    unsigned*       part   = (unsigned*)(ws + 2001024);
    int*            esrc   = (int*)(ws + 2003072);
    unsigned*       xh     = (unsigned*)(ws + 8403072);
    unsigned short* Wht    = (unsigned short*)(ws + 34003072);

    k_init<<<NCHUNK, 256, 0, stream>>>(deg, cnt, sums);
    k_cvt<<<25000, 256, 0, stream>>>(x, xh);
    k_cvtw<<<64, 256, 0, stream>>>(W, Wht);
    k_deg<<<NECH * 8, 256, 0, stream>>>(ei, deg, cnt);
    k_dinv<<<NCHUNK, 256, 0, stream>>>(deg, dinv);
    k_scan1<<<NCHUNK, 256, 0, stream>>>(cnt, part);
    k_scan2<<<1, 512, 0, stream>>>(part);
    k_scan3<<<NCHUNK, 256, 0, stream>>>(cnt, part, off, cursor);
    k_scatter<<<NECH * 8, 256, 0, stream>>>(ei, cursor, esrc);
    k_gather<<<25000, 256, 0, stream>>>(xh, dinv, off, cnt, esrc, out);
    k_gemm<<<782, 256, 0, stream>>>(out, Wht, b);
    k_stats<<<512, 256, 0, stream>>>(out, sums);
    k_apply<<<2048, 256, 0, stream>>>(out, gamma, beta, sums);
}

// Round 7
// 285.877 us; speedup vs baseline: 5.4047x; 1.3869x over previous
//
#include <hip/hip_runtime.h>
#include <math.h>

#define NN 100000
#define NE 1600000
#define D 128
#define BN_EPS 1e-5f
#define NCHUNK 391   // ceil(NN/256)
#define GSZ 12500    // NN / 8 (one node range per group)
#define NCH 64       // edge chunks
#define CH 25000     // NE / NCH
#define HW 6250      // packed words per histogram half (2 nodes/word)
#define HSTR 12500   // words per (group,chunk) hist slice: [0,HW)=cnt, [HW,2HW)=deg

typedef __attribute__((ext_vector_type(8))) short short8;
typedef __attribute__((ext_vector_type(4))) float f32x4;
typedef __attribute__((ext_vector_type(2))) float f32x2;

// ws layout (bytes):
// dinv   [0,        400000)
// sums   [800000,   801024)
// cnt    [801024,  1201024)
// off    [1201024, 1601024)
// part   [1601024, 1603072)
// esrc   [1603072,  8003072)   src per CSR slot
// shr    [8003072, 33603072)   hist scratch (25.6 MB), then reused as xh
// Wht    [33603072,33635840)

__device__ __forceinline__ unsigned bf_rne(float f) {
    unsigned u = __float_as_uint(f);
    return (u + 0x7fffu + ((u >> 16) & 1u)) >> 16;
}
__device__ __forceinline__ unsigned pk2(float lo, float hi) {
    return bf_rne(lo) | (bf_rne(hi) << 16);
}

// ---- kernel 1: per-(chunk,group) LDS histograms, packed 16-bit, atomic-free ----
// Counts per chunk are < 25000 < 2^16 -> packed halves can never overflow.
__global__ __launch_bounds__(512) void k_hist(const int* __restrict__ ei,
                                              unsigned* __restrict__ hist) {
    __shared__ unsigned loc[HSTR];  // 50 KB
    const int g = blockIdx.x & 7;
    const int t = blockIdx.x >> 3;
    const int lo = g * GSZ, hi = lo + GSZ;
    for (int j = threadIdx.x; j < HSTR; j += 512) loc[j] = 0u;
    __syncthreads();
    const int end = t * CH + CH;
    for (int i = t * CH + threadIdx.x; i < end; i += 512) {
        int r = __builtin_nontemporal_load(ei + i);
        int c = __builtin_nontemporal_load(ei + NE + i);
        if (r != c) {
            if (c >= lo && c < hi) {
                int q = c - lo;
                atomicAdd(&loc[q >> 1], 1u << ((q & 1) << 4));
            }
            if (r >= lo && r < hi) {
                int q = r - lo;
                atomicAdd(&loc[HW + (q >> 1)], 1u << ((q & 1) << 4));
            }
        }
    }
    __syncthreads();
    unsigned* dst = hist + (unsigned)(g * NCH + t) * HSTR;
    for (int j = threadIdx.x; j < HSTR; j += 512) dst[j] = loc[j];
}

// ---- kernel 2: reduce hists -> cnt, dinv; in-place per-chunk exclusive prefix --
__global__ __launch_bounds__(256) void k_reduce(unsigned* __restrict__ hist,
                                                unsigned* __restrict__ cnt,
                                                float* __restrict__ dinv) {
    int id = blockIdx.x * 256 + threadIdx.x;
    if (id >= 8 * HW) return;
    int g = id / HW;
    int w = id - g * HW;
    unsigned base = (unsigned)(g * NCH) * HSTR + w;
    unsigned run0 = 0, run1 = 0, s0 = 0, s1 = 0;
    for (int t = 0; t < NCH; ++t) {
        unsigned idx = base + (unsigned)t * HSTR;
        unsigned v = hist[idx];
        hist[idx] = run0 | (run1 << 16);  // exclusive prefix over chunks (packed)
        run0 += v & 0xffffu;
        run1 += v >> 16;
        unsigned d = hist[idx + HW];
        s0 += d & 0xffffu;
        s1 += d >> 16;
    }
    int n0 = g * GSZ + 2 * w;
    cnt[n0]     = run0;
    cnt[n0 + 1] = run1;
    dinv[n0]     = rsqrtf((float)(s0 + 1u));  // +1 self-loop
    dinv[n0 + 1] = rsqrtf((float)(s1 + 1u));
}

// ---------------- scan step 1: per-chunk sums -----------------------------------
__global__ __launch_bounds__(256) void k_scan1(const unsigned* __restrict__ cnt,
                                               unsigned* __restrict__ part) {
    __shared__ unsigned s[256];
    int i = blockIdx.x * 256 + threadIdx.x;
    unsigned v = (i < NN) ? cnt[i] : 0u;
    s[threadIdx.x] = v;
    __syncthreads();
    for (int o = 128; o > 0; o >>= 1) {
        if (threadIdx.x < o) s[threadIdx.x] += s[threadIdx.x + o];
        __syncthreads();
    }
    if (threadIdx.x == 0) part[blockIdx.x] = s[0];
}

// ------- scan step 2: exclusive scan of partials (1 block); zero BN sums --------
__global__ __launch_bounds__(512) void k_scan2(unsigned* __restrict__ part,
                                               float* __restrict__ sums) {
    __shared__ unsigned s[512];
    int t = threadIdx.x;
    if (t < 256) sums[t] = 0.f;
    unsigned v = (t < NCHUNK) ? part[t] : 0u;
    s[t] = v;
    __syncthreads();
    for (int o = 1; o < 512; o <<= 1) {
        unsigned add = (t >= o) ? s[t - o] : 0u;
        __syncthreads();
        s[t] += add;
        __syncthreads();
    }
    if (t < NCHUNK) part[t] = s[t] - v;  // exclusive
}

// ---------------- scan step 3: per-chunk exclusive offsets ----------------------
__global__ __launch_bounds__(256) void k_scan3(const unsigned* __restrict__ cnt,
                                               const unsigned* __restrict__ part,
                                               unsigned* __restrict__ off) {
    __shared__ unsigned s[256];
    int i = blockIdx.x * 256 + threadIdx.x;
    int t = threadIdx.x;
    unsigned v = (i < NN) ? cnt[i] : 0u;
    s[t] = v;
    __syncthreads();
    for (int o = 1; o < 256; o <<= 1) {
        unsigned add = (t >= o) ? s[t - o] : 0u;
        __syncthreads();
        s[t] += add;
        __syncthreads();
    }
    if (i < NN) off[i] = part[blockIdx.x] + s[t] - v;  // exclusive
}

// ---- kernel 3: scatter via LDS cursors (no global atomics) ---------------------
__global__ __launch_bounds__(512) void k_scatter(const int* __restrict__ ei,
                                                 const unsigned* __restrict__ off,
                                                 const unsigned* __restrict__ hist,
                                                 int* __restrict__ esrc) {
    __shared__ unsigned curs[GSZ];  // 50 KB
    const int g = blockIdx.x & 7;
    const int t = blockIdx.x >> 3;
    const int lo = g * GSZ, hi = lo + GSZ;
    const unsigned* hb = hist + (unsigned)(g * NCH + t) * HSTR;
    for (int j = threadIdx.x; j < GSZ; j += 512) {
        unsigned wd = hb[j >> 1];
        unsigned p = (j & 1) ? (wd >> 16) : (wd & 0xffffu);
        curs[j] = off[lo + j] + p;
    }
    __syncthreads();
    const int end = t * CH + CH;
    for (int i = t * CH + threadIdx.x; i < end; i += 512) {
        int r = __builtin_nontemporal_load(ei + i);
        int c = __builtin_nontemporal_load(ei + NE + i);
        if (r == c || c < lo || c >= hi) continue;
        unsigned pos = atomicAdd(&curs[c - lo], 1u);  // LDS atomic
        esrc[pos] = r;                                // L2-local slice, plain store
    }
}

// ---------------- kernel 4: x -> bf16 packed (after scatter; shr reuse) ---------
__global__ void k_cvt(const float* __restrict__ x, unsigned* __restrict__ xh) {
    int i = blockIdx.x * blockDim.x + threadIdx.x;
    if (i < NN * 64) {
        f32x2 v = __builtin_nontemporal_load((const f32x2*)x + i);
        xh[i] = pk2(v.x, v.y);
    }
}

// ---------------- kernel 4b: W[k][c] -> Wht[c][k] bf16 --------------------------
__global__ void k_cvtw(const float* __restrict__ W, unsigned short* __restrict__ Wht) {
    int i = blockIdx.x * blockDim.x + threadIdx.x;  // i = k*128 + c
    if (i < D * D) {
        int k = i >> 7, c = i & 127;
        Wht[c * D + k] = (unsigned short)bf_rne(W[i]);
    }
}

// -------- kernel 5: gather bf16 rows: out_c = dc*(dc*x_c + sum dr*x_r) ----------
__global__ __launch_bounds__(256) void k_gather(const unsigned* __restrict__ xh,
                                                const float* __restrict__ dinv,
                                                const unsigned* __restrict__ off,
                                                const unsigned* __restrict__ cnt,
                                                const int* __restrict__ esrc,
                                                float* __restrict__ out) {
    const int lane = threadIdx.x & 63;
    const int wave = threadIdx.x >> 6;
    const int c = blockIdx.x * 4 + wave;
    if (c >= NN) return;

    const float dc = dinv[c];
    unsigned xc = xh[c * 64 + lane];
    float al = dc * __uint_as_float(xc << 16);
    float ah = dc * __uint_as_float(xc & 0xffff0000u);

    const int base = off[c];
    const int n = cnt[c];
    int i = 0;
    for (; i + 4 <= n; i += 4) {
        int s0 = esrc[base + i], s1 = esrc[base + i + 1];
        int s2 = esrc[base + i + 2], s3 = esrc[base + i + 3];
        float w0 = dinv[s0], w1 = dinv[s1], w2 = dinv[s2], w3 = dinv[s3];
        unsigned p0 = xh[s0 * 64 + lane], p1 = xh[s1 * 64 + lane];
        unsigned p2 = xh[s2 * 64 + lane], p3 = xh[s3 * 64 + lane];
        al = fmaf(w0, __uint_as_float(p0 << 16), al);
        ah = fmaf(w0, __uint_as_float(p0 & 0xffff0000u), ah);
        al = fmaf(w1, __uint_as_float(p1 << 16), al);
        ah = fmaf(w1, __uint_as_float(p1 & 0xffff0000u), ah);
        al = fmaf(w2, __uint_as_float(p2 << 16), al);
        ah = fmaf(w2, __uint_as_float(p2 & 0xffff0000u), ah);
        al = fmaf(w3, __uint_as_float(p3 << 16), al);
        ah = fmaf(w3, __uint_as_float(p3 & 0xffff0000u), ah);
    }
    for (; i < n; ++i) {
        int s0 = esrc[base + i];
        float w0 = dinv[s0];
        unsigned p0 = xh[s0 * 64 + lane];
        al = fmaf(w0, __uint_as_float(p0 << 16), al);
        ah = fmaf(w0, __uint_as_float(p0 & 0xffff0000u), ah);
    }
    al *= dc;
    ah *= dc;
    *(float2*)&out[c * D + 2 * lane] = make_float2(al, ah);
}

// -------- kernel 6: in-place MFMA GEMM: out_tile = relu(out_tile @ W + b) -------
__global__ __launch_bounds__(256, 1) void k_gemm(float* __restrict__ out,
                                                 const unsigned short* __restrict__ Wht,
                                                 const float* __restrict__ b) {
    const int lane = threadIdx.x & 63;
    const int wv = threadIdx.x >> 6;
    const int l15 = lane & 15, l4 = lane >> 4;

    short8 bfr[8][4];
    #pragma unroll
    for (int n = 0; n < 8; ++n)
        #pragma unroll
        for (int kk = 0; kk < 4; ++kk)
            bfr[n][kk] = *(const short8*)(Wht + (n * 16 + l15) * D + kk * 32 + l4 * 8);

    float bias8[8];
    #pragma unroll
    for (int n = 0; n < 8; ++n) bias8[n] = b[n * 16 + l15];

    const int gw = blockIdx.x * 4 + wv;
    #pragma unroll
    for (int t = 0; t < 2; ++t) {
        const int tile = gw * 2 + t;
        if (tile < NN / 16) {
            const int row0 = tile * 16;
            short8 af[4];
            #pragma unroll
            for (int kk = 0; kk < 4; ++kk) {
                const float* ar = out + (row0 + l15) * D + kk * 32 + l4 * 8;
                float4 a0 = *(const float4*)ar;
                float4 a1 = *(const float4*)(ar + 4);
                union { short8 s; unsigned u[4]; } cv;
                cv.u[0] = pk2(a0.x, a0.y);
                cv.u[1] = pk2(a0.z, a0.w);
                cv.u[2] = pk2(a1.x, a1.y);
                cv.u[3] = pk2(a1.z, a1.w);
                af[kk] = cv.s;
            }
            f32x4 acc[8];
            #pragma unroll
            for (int n = 0; n < 8; ++n) acc[n] = (f32x4){0.f, 0.f, 0.f, 0.f};
            #pragma unroll
            for (int n = 0; n < 8; ++n)
                #pragma unroll
                for (int kk = 0; kk < 4; ++kk)
                    acc[n] = __builtin_amdgcn_mfma_f32_16x16x32_bf16(af[kk], bfr[n][kk],
                                                                     acc[n], 0, 0, 0);
            #pragma unroll
            for (int n = 0; n < 8; ++n)
                #pragma unroll
                for (int r = 0; r < 4; ++r) {
                    int row = row0 + l4 * 4 + r;
                    out[row * D + n * 16 + l15] = fmaxf(acc[n][r] + bias8[n], 0.f);
                }
        }
    }
}

// ------------- kernel 7: BN stats (sum, sumsq per channel) ----------------------
__global__ __launch_bounds__(256) void k_stats(const float* __restrict__ out,
                                               float* __restrict__ sums) {
    const int c  = threadIdx.x & 127;
    const int rg = threadIdx.x >> 7;
    float s = 0.f, s2 = 0.f;
    for (int row = blockIdx.x * 2 + rg; row < NN; row += gridDim.x * 2) {
        float v = out[row * D + c];
        s += v;
        s2 = fmaf(v, v, s2);
    }
    __shared__ float r1[128], r2[128];
    if (rg == 1) { r1[c] = s; r2[c] = s2; }
    __syncthreads();
    if (rg == 0) {
        s += r1[c];
        s2 += r2[c];
        unsafeAtomicAdd(&sums[c], s);
        unsafeAtomicAdd(&sums[128 + c], s2);
    }
}

// ------------- kernel 8: out = out * scale + shift  (BN affine) -----------------
__global__ __launch_bounds__(256) void k_apply(float* __restrict__ out,
                                               const float* __restrict__ gamma,
                                               const float* __restrict__ beta,
                                               const float* __restrict__ sums) {
    const float invN = 1.f / (float)NN;
    const int tid = blockIdx.x * blockDim.x + threadIdx.x;
    const int stride = gridDim.x * blockDim.x;
    const int c4 = (tid & 31) * 4;

    float4 g4 = *(const float4*)&gamma[c4];
    float4 be = *(const float4*)&beta[c4];
    float4 s4 = *(const float4*)&sums[c4];
    float4 q4 = *(const float4*)&sums[128 + c4];

    float mx = s4.x * invN, my = s4.y * invN, mz = s4.z * invN, mw = s4.w * invN;
    float scx = g4.x * rsqrtf(fmaxf(q4.x * invN - mx * mx, 0.f) + BN_EPS);
    float scy = g4.y * rsqrtf(fmaxf(q4.y * invN - my * my, 0.f) + BN_EPS);
    float scz = g4.z * rsqrtf(fmaxf(q4.z * invN - mz * mz, 0.f) + BN_EPS);
    float scw = g4.w * rsqrtf(fmaxf(q4.w * invN - mw * mw, 0.f) + BN_EPS);
    float shx = be.x - mx * scx, shy = be.y - my * scy;
    float shz = be.z - mz * scz, shw = be.w - mw * scw;

    for (int idx = tid; idx < NN * (D / 4); idx += stride) {
        float4 a = ((const float4*)out)[idx];
        a.x = a.x * scx + shx;
        a.y = a.y * scy + shy;
        a.z = a.z * scz + shz;
        a.w = a.w * scw + shw;
        ((float4*)out)[idx] = a;
    }
}

extern "C" void kernel_launch(void* const* d_in, const int* in_sizes, int n_in,
                              void* d_out, int out_size, void* d_ws, size_t ws_size,
                              hipStream_t stream) {
    const float* x     = (const float*)d_in[0];
    const int*   ei    = (const int*)d_in[1];
    const float* W     = (const float*)d_in[2];
    const float* b     = (const float*)d_in[3];
    const float* gamma = (const float*)d_in[4];
    const float* beta  = (const float*)d_in[5];
    float*       out   = (float*)d_out;

    char* ws = (char*)d_ws;
    float*          dinv = (float*)ws;
    float*          sums = (float*)(ws + 800000);
    unsigned*       cnt  = (unsigned*)(ws + 801024);
    unsigned*       off  = (unsigned*)(ws + 1201024);
    unsigned*       part = (unsigned*)(ws + 1601024);
    int*            esrc = (int*)(ws + 1603072);
    unsigned*       hist = (unsigned*)(ws + 8003072);   // 25.6 MB, reused as xh
    unsigned*       xh   = (unsigned*)(ws + 8003072);
    unsigned short* Wht  = (unsigned short*)(ws + 33603072);

    k_hist<<<NCH * 8, 512, 0, stream>>>(ei, hist);
    k_reduce<<<(8 * HW + 255) / 256, 256, 0, stream>>>(hist, cnt, dinv);
    k_scan1<<<NCHUNK, 256, 0, stream>>>(cnt, part);
    k_scan2<<<1, 512, 0, stream>>>(part, sums);
    k_scan3<<<NCHUNK, 256, 0, stream>>>(cnt, part, off);
    k_scatter<<<NCH * 8, 512, 0, stream>>>(ei, off, hist, esrc);
    k_cvt<<<25000, 256, 0, stream>>>(x, xh);
    k_cvtw<<<64, 256, 0, stream>>>(W, Wht);
    k_gather<<<25000, 256, 0, stream>>>(xh, dinv, off, cnt, esrc, out);
    k_gemm<<<782, 256, 0, stream>>>(out, Wht, b);
    k_stats<<<512, 256, 0, stream>>>(out, sums);
    k_apply<<<2048, 256, 0, stream>>>(out, gamma, beta, sums);
}